// Round 2
// baseline (148.109 us; speedup 1.0000x reference)
//
#include <hip/hip_runtime.h>

#define HW 4096
#define NC 256
#define NK 16
#define NB 4
#define BN_EPS 1e-5f

// ws layout in floats
#define OFF_BNSUM   0
#define OFF_BNSQ    16
#define OFF_SR      32
#define OFF_SRR     96
#define OFF_SCALE   160
#define OFF_SX      224
#define OFF_SXX     1248
#define OFF_CROSS   2272
#define ACC_FLOATS  18656
#define OFF_CW      18656
// cw: [b][k*4096+i] = 4*65536 floats; total ws = 280800 floats (~1.1 MB)

// ---------------- Kernel 1: 1x1 conv + BN batch-stat sums ----------------
// grid 128 = 4(b) x 32(ich of 128 spatial), block 256.
// thread t: ch = t>>7 (c-half), il = t&127 (spatial within chunk).
__global__ __launch_bounds__(256) void k_conv(const float* __restrict__ x,
                                              const float* __restrict__ w,
                                              float* __restrict__ cw,
                                              float* __restrict__ bn_sum,
                                              float* __restrict__ bn_sq) {
    __shared__ float wl[NK * NC];     // 16 KB, same flat layout as w
    __shared__ float red[NK * 128];   // 8 KB handoff, [k][il]
    int bid = blockIdx.x;
    int b   = bid >> 5;
    int ich = bid & 31;
    int t   = threadIdx.x;
    int ch  = t >> 7;
    int il  = t & 127;
    int i   = ich * 128 + il;

    for (int idx = t; idx < NK * NC; idx += 256) wl[idx] = w[idx];
    __syncthreads();

    float acc[NK];
    #pragma unroll
    for (int k = 0; k < NK; ++k) acc[k] = 0.f;

    const float* xp = x + (size_t)(b * NC + ch * 128) * HW + i;
    const float* wp = wl + ch * 128;
    #pragma unroll 4
    for (int cc = 0; cc < 128; ++cc) {
        float xv = xp[(size_t)cc * HW];
        #pragma unroll
        for (int k = 0; k < NK; ++k) acc[k] = fmaf(wp[k * NC + cc], xv, acc[k]);
    }
    __syncthreads();

    if (ch == 1) {
        #pragma unroll
        for (int k = 0; k < NK; ++k) red[k * 128 + il] = acc[k];  // conflict-free
    }
    __syncthreads();

    if (ch == 0) {
        float* cwp = cw + (size_t)b * 65536 + i;
        float s1 = 0.f;  // placeholders to keep per-k in regs
        (void)s1;
        #pragma unroll
        for (int k = 0; k < NK; ++k) {
            float v = acc[k] + red[k * 128 + il];
            acc[k] = v;
            cwp[(size_t)k * HW] = v;
        }
        // BN partial sums: wave-level shuffle reduce (2 waves of ch==0)
        int lane = t & 63;
        #pragma unroll
        for (int k = 0; k < NK; ++k) {
            float v1 = acc[k];
            float v2 = v1 * v1;
            #pragma unroll
            for (int off = 32; off > 0; off >>= 1) {
                v1 += __shfl_down(v1, off);
                v2 += __shfl_down(v2, off);
            }
            if (lane == 0) {
                atomicAdd(bn_sum + k, v1);
                atomicAdd(bn_sq + k, v2);
            }
        }
    }
}

// ---------------- Kernel 2: BN apply + scale/Sr/Srr + Cross + Sx/Sxx ----------------
// grid 128 = 4(b) x 32(ich, 128 spatial each), block 256 (thread = channel c for Cross)
__global__ __launch_bounds__(256) void k_main(const float* __restrict__ x,
                                              const float* __restrict__ gamma,
                                              const float* __restrict__ beta,
                                              float* __restrict__ ws) {
    int bid = blockIdx.x;
    int b   = bid >> 5;
    int ich = bid & 31;
    int kp  = ich >> 1;   // BN channel for this whole flat slab
    int t   = threadIdx.x;

    const float* cw = ws + OFF_CW;
    float mean = ws[OFF_BNSUM + kp] * (1.f / 16384.f);
    float var  = ws[OFF_BNSQ + kp] * (1.f / 16384.f) - mean * mean;
    float aa   = gamma[kp] * rsqrtf(var + BN_EPS);
    float bb   = beta[kp] - mean * aa;

    __shared__ float rl[2048];
    __shared__ float red1[256], red2[256];

    size_t fb = (size_t)b * 65536 + (size_t)ich * 2048;
    float sr = 0.f, srr = 0.f;
    #pragma unroll
    for (int s = 0; s < 8; ++s) {
        int off = t + s * 256;
        float v = cw[fb + off];
        v = fmaxf(fmaf(v, aa, bb), 0.f);
        rl[off] = v;
        sr += v;
        srr += v * v;
    }
    red1[t] = sr; red2[t] = srr;
    __syncthreads();

    // per-new-k sums: flat offset ≡ t (mod 16) selects k2 = t
    if (t < 16) {
        float s1 = 0.f, s2 = 0.f;
        for (int m = t; m < 256; m += 16) { s1 += red1[m]; s2 += red2[m]; }
        atomicAdd(ws + OFF_SR  + b * 16 + t, s1);
        atomicAdd(ws + OFF_SRR + b * 16 + t, s2);
        red1[t] = s1;   // lane t reads only m≡t(16), writes t — no cross-lane hazard
    }
    __syncthreads();
    if (t == 0) {
        float tot = 0.f;
        for (int m = 0; m < 16; ++m) tot += red1[m];
        atomicAdd(ws + OFF_SCALE + b * 16 + kp, tot);  // original-channel scale
    }

    // Cross[b,k,c] = sum_i x[b,c,i] * r[b,i,k]; thread t = channel c
    int c = t;
    const float4* xp = (const float4*)(x + (size_t)(b * NC + c) * HW + ich * 128);
    float acc[NK];
    #pragma unroll
    for (int k = 0; k < NK; ++k) acc[k] = 0.f;
    float xs = 0.f, xs2 = 0.f;

    #pragma unroll 2
    for (int s = 0; s < 32; ++s) {
        float4 xv = xp[s];
        float xe[4] = {xv.x, xv.y, xv.z, xv.w};
        #pragma unroll
        for (int e = 0; e < 4; ++e) {
            float v = xe[e];
            xs += v; xs2 += v * v;
            const float* rp = rl + (s * 4 + e) * 16;  // broadcast across lanes
            #pragma unroll
            for (int k = 0; k < NK; ++k) acc[k] = fmaf(v, rp[k], acc[k]);
        }
    }

    atomicAdd(ws + OFF_SX  + b * 256 + c, xs);
    atomicAdd(ws + OFF_SXX + b * 256 + c, xs2);
    #pragma unroll
    for (int k = 0; k < NK; ++k)
        atomicAdd(ws + OFF_CROSS + (b * 16 + k) * 256 + c, acc[k]);
}

// ---------------- Kernel 3: softmax + output ----------------
// grid 4 (b), block 256 (thread = c)
__global__ __launch_bounds__(256) void k_final(const float* __restrict__ ws,
                                               float* __restrict__ out) {
    int b = blockIdx.x;
    int c = threadIdx.x;
    float sx  = ws[OFF_SX  + b * 256 + c];
    float sxx = ws[OFF_SXX + b * 256 + c];

    float sl2[NK];
    float mx = -1e30f;
    #pragma unroll
    for (int k = 0; k < NK; ++k) {
        float cr  = ws[OFF_CROSS + (b * 16 + k) * 256 + c];
        float sc  = ws[OFF_SCALE + b * 16 + k] * (1.f / 4096.f);
        float srr = ws[OFF_SRR   + b * 16 + k];
        float v = sc * (sxx - 2.f * cr + srr);
        sl2[k] = v;
        mx = fmaxf(mx, v);
    }
    float den = 0.f;
    #pragma unroll
    for (int k = 0; k < NK; ++k) {
        float e = __expf(sl2[k] - mx);
        sl2[k] = e;
        den += e;
    }
    float inv = 1.f / den;
    #pragma unroll
    for (int k = 0; k < NK; ++k) {
        float srk = ws[OFF_SR + b * 16 + k];
        out[(size_t)(b * 16 + k) * 256 + c] = sl2[k] * inv * (sx - srk);
    }
}

extern "C" void kernel_launch(void* const* d_in, const int* in_sizes, int n_in,
                              void* d_out, int out_size, void* d_ws, size_t ws_size,
                              hipStream_t stream) {
    const float* x     = (const float*)d_in[0];
    const float* w     = (const float*)d_in[1];
    const float* gamma = (const float*)d_in[2];
    const float* beta  = (const float*)d_in[3];
    float* ws  = (float*)d_ws;
    float* out = (float*)d_out;

    hipMemsetAsync(ws, 0, ACC_FLOATS * sizeof(float), stream);
    k_conv<<<128, 256, 0, stream>>>(x, w, ws + OFF_CW,
                                    ws + OFF_BNSUM, ws + OFF_BNSQ);
    k_main<<<128, 256, 0, stream>>>(x, gamma, beta, ws);
    k_final<<<4, 256, 0, stream>>>(ws, out);
}

// Round 3
// 137.565 us; speedup vs baseline: 1.0766x; 1.0766x over previous
//
#include <hip/hip_runtime.h>

#define HW 4096
#define NC 256
#define NK 16
#define BN_EPS 1e-5f

// ws layout in floats
#define OFF_BNSUM   0
#define OFF_BNSQ    16
#define OFF_SR      32
#define OFF_SRR     96
#define OFF_SCALE   160
#define OFF_SX      224
#define OFF_SXX     1248
#define OFF_CROSS   2272
#define ACC_FLOATS  18656
#define OFF_CW      18656
#define OFF_PCX     (OFF_CW + 262144)
#define PCX_FLOATS  (4 * 64 * NK * 256)
#define WS_NEED_PCX ((size_t)(OFF_PCX + PCX_FLOATS) * sizeof(float))

#define FMA16(v, rp)                                   \
    {                                                  \
        const float4* rq_ = (const float4*)(rp);       \
        float4 r0_ = rq_[0], r1_ = rq_[1];             \
        float4 r2_ = rq_[2], r3_ = rq_[3];             \
        acc[0]  = fmaf(v, r0_.x, acc[0]);              \
        acc[1]  = fmaf(v, r0_.y, acc[1]);              \
        acc[2]  = fmaf(v, r0_.z, acc[2]);              \
        acc[3]  = fmaf(v, r0_.w, acc[3]);              \
        acc[4]  = fmaf(v, r1_.x, acc[4]);              \
        acc[5]  = fmaf(v, r1_.y, acc[5]);              \
        acc[6]  = fmaf(v, r1_.z, acc[6]);              \
        acc[7]  = fmaf(v, r1_.w, acc[7]);              \
        acc[8]  = fmaf(v, r2_.x, acc[8]);              \
        acc[9]  = fmaf(v, r2_.y, acc[9]);              \
        acc[10] = fmaf(v, r2_.z, acc[10]);             \
        acc[11] = fmaf(v, r2_.w, acc[11]);             \
        acc[12] = fmaf(v, r3_.x, acc[12]);             \
        acc[13] = fmaf(v, r3_.y, acc[13]);             \
        acc[14] = fmaf(v, r3_.z, acc[14]);             \
        acc[15] = fmaf(v, r3_.w, acc[15]);             \
    }

// ---------------- Kernel 1: 1x1 conv + BN batch-stat sums ----------------
// grid 512 = 4(b) x 128(ich of 32 i), block 256 = 8(cp of 32 c) x 32(il)
__global__ __launch_bounds__(256) void k_conv(const float* __restrict__ x,
                                              const float* __restrict__ w,
                                              float* __restrict__ cw,
                                              float* __restrict__ bn_sum,
                                              float* __restrict__ bn_sq) {
    __shared__ float wlT[NC * NK];      // [c][k], 16 KB
    __shared__ float red[8 * NK * 32];  // [cp][k][il], 16 KB
    int bid = blockIdx.x;
    int b   = bid >> 7;
    int ich = bid & 127;
    int t   = threadIdx.x;
    int cp  = t >> 5;
    int il  = t & 31;
    int i   = ich * 32 + il;

    for (int idx = t; idx < NC * NK; idx += 256) {
        int k = idx >> 8, c = idx & 255;
        wlT[c * NK + k] = w[idx];
    }
    __syncthreads();

    float acc[NK];
    #pragma unroll
    for (int k = 0; k < NK; ++k) acc[k] = 0.f;

    const float* xp = x + (size_t)(b * NC + cp * 32) * HW + i;
    #pragma unroll
    for (int cc = 0; cc < 32; ++cc) {
        float xv = xp[(size_t)cc * HW];
        FMA16(xv, wlT + (cp * 32 + cc) * NK);
    }

    #pragma unroll
    for (int k = 0; k < NK; ++k) red[(cp * NK + k) * 32 + il] = acc[k];
    __syncthreads();

    #pragma unroll
    for (int half = 0; half < 2; ++half) {
        int o = t + half * 256;          // o = k*32 + ilo
        float s = 0.f;
        #pragma unroll
        for (int cp2 = 0; cp2 < 8; ++cp2) s += red[cp2 * (NK * 32) + o];
        int k = o >> 5, ilo = o & 31;
        cw[(size_t)b * 65536 + (size_t)k * HW + ich * 32 + ilo] = s;
        float s2 = s * s;
        #pragma unroll
        for (int off = 16; off > 0; off >>= 1) {
            s  += __shfl_down(s, off, 32);
            s2 += __shfl_down(s2, off, 32);
        }
        if (ilo == 0) {
            atomicAdd(bn_sum + k, s);
            atomicAdd(bn_sq + k, s2);
        }
    }
}

// ---------------- Kernel 2: BN apply + Sr/Srr/scale + Cross partials + Sx/Sxx --
// grid 256 = 4(b) x 64(ich of 64 i / 1024 flat r), block 256 (t = channel c)
template <bool PCX>
__global__ __launch_bounds__(256) void k_main(const float* __restrict__ x,
                                              const float* __restrict__ gamma,
                                              const float* __restrict__ beta,
                                              float* __restrict__ ws,
                                              float* __restrict__ pcx) {
    int bid = blockIdx.x;
    int b   = bid >> 6;
    int ich = bid & 63;
    int kp  = ich >> 2;   // flat slab of 1024 lies inside one BN channel
    int t   = threadIdx.x;

    const float* cw = ws + OFF_CW;
    float mean = ws[OFF_BNSUM + kp] * (1.f / 16384.f);
    float var  = ws[OFF_BNSQ + kp] * (1.f / 16384.f) - mean * mean;
    float aa   = gamma[kp] * rsqrtf(var + BN_EPS);
    float bb   = beta[kp] - mean * aa;

    __shared__ float rl[1024];
    __shared__ float red1[256], red2[256];

    size_t fb = (size_t)b * 65536 + (size_t)ich * 1024;
    float sr = 0.f, srr = 0.f;
    #pragma unroll
    for (int s = 0; s < 4; ++s) {
        int j = t + s * 256;             // j & 15 == t & 15 (k2 constant/thread)
        float v = cw[fb + j];
        v = fmaxf(fmaf(v, aa, bb), 0.f);
        rl[j] = v;
        sr += v; srr += v * v;
    }
    red1[t] = sr; red2[t] = srr;
    __syncthreads();

    if (t < 16) {
        float s1 = 0.f, s2 = 0.f;
        for (int m = t; m < 256; m += 16) { s1 += red1[m]; s2 += red2[m]; }
        atomicAdd(ws + OFF_SR  + b * 16 + t, s1);
        atomicAdd(ws + OFF_SRR + b * 16 + t, s2);
        red1[t] = s1;  // lane t reads only m≡t (mod 16) above; same-wave in-order
    }
    __syncthreads();
    if (t == 0) {
        float tot = 0.f;
        #pragma unroll
        for (int m = 0; m < 16; ++m) tot += red1[m];
        atomicAdd(ws + OFF_SCALE + b * 16 + kp, tot);
    }

    // Cross partial: thread t = channel c over 64 spatial of this slab
    int c = t;
    const float4* xp = (const float4*)(x + (size_t)(b * NC + c) * HW + ich * 64);
    float acc[NK];
    #pragma unroll
    for (int k = 0; k < NK; ++k) acc[k] = 0.f;
    float xs = 0.f, xs2 = 0.f;

    #pragma unroll
    for (int s = 0; s < 16; ++s) {
        float4 xq = xp[s];
        float xe[4] = {xq.x, xq.y, xq.z, xq.w};
        #pragma unroll
        for (int e = 0; e < 4; ++e) {
            float v = xe[e];
            xs += v; xs2 += v * v;
            FMA16(v, rl + (s * 4 + e) * NK);   // broadcast LDS float4 reads
        }
    }

    atomicAdd(ws + OFF_SX  + b * 256 + c, xs);
    atomicAdd(ws + OFF_SXX + b * 256 + c, xs2);
    if (PCX) {
        float* pp = pcx + (size_t)(b * 64 + ich) * (NK * 256) + c;
        #pragma unroll
        for (int k = 0; k < NK; ++k) pp[(size_t)k * 256] = acc[k];
    } else {
        #pragma unroll
        for (int k = 0; k < NK; ++k)
            atomicAdd(ws + OFF_CROSS + (b * 16 + k) * 256 + c, acc[k]);
    }
}

// ---------------- Kernel 3: reduce Cross partials ----------------
// grid 256 = 4(b) x 16(k) x 4(g of 16 slabs), block 256 (t = c)
__global__ __launch_bounds__(256) void k_red(const float* __restrict__ pcx,
                                             float* __restrict__ ws) {
    int bid = blockIdx.x;
    int b = bid >> 6;
    int k = (bid >> 2) & 15;
    int g = bid & 3;
    int c = threadIdx.x;
    float s = 0.f;
    #pragma unroll
    for (int m = 0; m < 16; ++m) {
        int ich = g * 16 + m;
        s += pcx[(size_t)(b * 64 + ich) * (NK * 256) + (size_t)k * 256 + c];
    }
    atomicAdd(ws + OFF_CROSS + (b * 16 + k) * 256 + c, s);
}

// ---------------- Kernel 4: softmax + output ----------------
// grid 4 (b), block 256 (t = c)
__global__ __launch_bounds__(256) void k_final(const float* __restrict__ ws,
                                               float* __restrict__ out) {
    int b = blockIdx.x;
    int c = threadIdx.x;
    float sx  = ws[OFF_SX  + b * 256 + c];
    float sxx = ws[OFF_SXX + b * 256 + c];

    float sl2[NK];
    float mx = -1e30f;
    #pragma unroll
    for (int k = 0; k < NK; ++k) {
        float cr  = ws[OFF_CROSS + (b * 16 + k) * 256 + c];
        float sc  = ws[OFF_SCALE + b * 16 + k] * (1.f / 4096.f);
        float srr = ws[OFF_SRR   + b * 16 + k];
        float v = sc * (sxx - 2.f * cr + srr);
        sl2[k] = v;
        mx = fmaxf(mx, v);
    }
    float den = 0.f;
    #pragma unroll
    for (int k = 0; k < NK; ++k) {
        float e = __expf(sl2[k] - mx);
        sl2[k] = e;
        den += e;
    }
    float inv = 1.f / den;
    #pragma unroll
    for (int k = 0; k < NK; ++k) {
        float srk = ws[OFF_SR + b * 16 + k];
        out[(size_t)(b * 16 + k) * 256 + c] = sl2[k] * inv * (sx - srk);
    }
}

extern "C" void kernel_launch(void* const* d_in, const int* in_sizes, int n_in,
                              void* d_out, int out_size, void* d_ws, size_t ws_size,
                              hipStream_t stream) {
    const float* x     = (const float*)d_in[0];
    const float* w     = (const float*)d_in[1];
    const float* gamma = (const float*)d_in[2];
    const float* beta  = (const float*)d_in[3];
    float* ws  = (float*)d_ws;
    float* out = (float*)d_out;

    bool use_pcx = ws_size >= WS_NEED_PCX;   // constant across calls: graph-safe

    hipMemsetAsync(ws, 0, ACC_FLOATS * sizeof(float), stream);
    k_conv<<<512, 256, 0, stream>>>(x, w, ws + OFF_CW,
                                    ws + OFF_BNSUM, ws + OFF_BNSQ);
    if (use_pcx) {
        k_main<true><<<256, 256, 0, stream>>>(x, gamma, beta, ws, ws + OFF_PCX);
        k_red<<<256, 256, 0, stream>>>(ws + OFF_PCX, ws);
    } else {
        k_main<false><<<256, 256, 0, stream>>>(x, gamma, beta, ws, nullptr);
    }
    k_final<<<4, 256, 0, stream>>>(ws, out);
}

// Round 6
// 102.327 us; speedup vs baseline: 1.4474x; 1.3444x over previous
//
#include <hip/hip_runtime.h>

#define BN_EPS 1e-5f

// ws layout (floats) — every region fully written each launch (no memset needed)
#define OFF_PBN     0          // [256 blk][32]  k_conv BN partials (sum k<16, sq 16+k)
#define OFF_PSR     8192       // [512 blk][32]  k_main SR/SRR partials
#define OFF_PSX     24576      // [512 blk][256] k_main SX partials
#define OFF_PSXX    155648     // [512 blk][256] k_main SXX partials
#define OFF_CROSSR  286720     // [4 sg][4 b][16 k][256 c] k_red outputs
#define OFF_CW      352256     // [b][k][4096] = 262144
#define OFF_PCX     614400     // [(b*128+s)][16][256] = 2097152
#define WS_NEED     ((size_t)(OFF_PCX + 2097152) * sizeof(float))

#define CONV_FMA(W, K0)                                  \
    acc[K0][0] = fmaf(W, xv.x, acc[K0][0]);              \
    acc[K0][1] = fmaf(W, xv.y, acc[K0][1]);              \
    acc[K0][2] = fmaf(W, xv.z, acc[K0][2]);              \
    acc[K0][3] = fmaf(W, xv.w, acc[K0][3]);

#define FMA16(v, rp)                                     \
    {                                                    \
        const float4* rq_ = (const float4*)(rp);         \
        float4 r0_ = rq_[0], r1_ = rq_[1];               \
        float4 r2_ = rq_[2], r3_ = rq_[3];               \
        acc[0]  = fmaf(v, r0_.x, acc[0]);                \
        acc[1]  = fmaf(v, r0_.y, acc[1]);                \
        acc[2]  = fmaf(v, r0_.z, acc[2]);                \
        acc[3]  = fmaf(v, r0_.w, acc[3]);                \
        acc[4]  = fmaf(v, r1_.x, acc[4]);                \
        acc[5]  = fmaf(v, r1_.y, acc[5]);                \
        acc[6]  = fmaf(v, r1_.z, acc[6]);                \
        acc[7]  = fmaf(v, r1_.w, acc[7]);                \
        acc[8]  = fmaf(v, r2_.x, acc[8]);                \
        acc[9]  = fmaf(v, r2_.y, acc[9]);                \
        acc[10] = fmaf(v, r2_.z, acc[10]);               \
        acc[11] = fmaf(v, r2_.w, acc[11]);               \
        acc[12] = fmaf(v, r3_.x, acc[12]);               \
        acc[13] = fmaf(v, r3_.y, acc[13]);               \
        acc[14] = fmaf(v, r3_.z, acc[14]);               \
        acc[15] = fmaf(v, r3_.w, acc[15]);               \
    }

// ---------------- Kernel 1: 1x1 conv + BN partial sums (no atomics) ----------------
// grid 256 = 4(b) x 64(ich of 64 i); block 256: cp = t&15 (16 c each), il = t>>4.
// All 16 cp sit in lane bits 0-3 of one wave -> in-wave reduce-scatter over c;
// lane ends owning k = bitrev4(cp).
__global__ __launch_bounds__(256, 2) void k_conv(const float* __restrict__ x,
                                                 const float* __restrict__ w,
                                                 float* __restrict__ cw,
                                                 float* __restrict__ pbn) {
    __shared__ float wlT[4124];      // wlT[c*16 + (c>>5)*4 + k]  (skew: 2-way max)
    __shared__ float bnl[4][32];
    int bid = blockIdx.x;
    int b   = bid >> 6;
    int ich = bid & 63;
    int t   = threadIdx.x;
    int cp  = t & 15;
    int il  = t >> 4;                // 0..15
    int wv  = t >> 6;

    for (int m = t; m < 4096; m += 256) {
        int k = m >> 8, c = m & 255;
        wlT[(c << 4) + ((c >> 5) << 2) + k] = w[m];
    }
    __syncthreads();

    float acc[16][4];
    #pragma unroll
    for (int k = 0; k < 16; ++k) {
        #pragma unroll
        for (int e = 0; e < 4; ++e) acc[k][e] = 0.f;
    }

    const float* xp = x + (size_t)(b * 256 + cp * 16) * 4096 + ich * 64 + il * 4;
    #pragma unroll
    for (int cc = 0; cc < 16; ++cc) {
        float4 xv = *(const float4*)(xp + (size_t)cc * 4096);
        int c = cp * 16 + cc;
        const float4* wr = (const float4*)&wlT[(c << 4) + ((c >> 5) << 2)];
        float4 w0 = wr[0], w1 = wr[1], w2 = wr[2], w3 = wr[3];
        CONV_FMA(w0.x, 0)  CONV_FMA(w0.y, 1)  CONV_FMA(w0.z, 2)  CONV_FMA(w0.w, 3)
        CONV_FMA(w1.x, 4)  CONV_FMA(w1.y, 5)  CONV_FMA(w1.z, 6)  CONV_FMA(w1.w, 7)
        CONV_FMA(w2.x, 8)  CONV_FMA(w2.y, 9)  CONV_FMA(w2.z, 10) CONV_FMA(w2.w, 11)
        CONV_FMA(w3.x, 12) CONV_FMA(w3.y, 13) CONV_FMA(w3.z, 14) CONV_FMA(w3.w, 15)
    }

    // reduce-scatter over cp (lane bits 0-3); final k = bit-reverse(cp).
    float r8[8][4];
    #pragma unroll
    for (int r = 0; r < 8; ++r) {
        #pragma unroll
        for (int e = 0; e < 4; ++e) {
            float lo = acc[r][e]     + __shfl_xor(acc[r][e], 1);
            float hi = acc[r + 8][e] + __shfl_xor(acc[r + 8][e], 1);
            r8[r][e] = (cp & 1) ? hi : lo;
        }
    }
    float r4v[4][4];
    #pragma unroll
    for (int r = 0; r < 4; ++r) {
        #pragma unroll
        for (int e = 0; e < 4; ++e) {
            float lo = r8[r][e]     + __shfl_xor(r8[r][e], 2);
            float hi = r8[r + 4][e] + __shfl_xor(r8[r + 4][e], 2);
            r4v[r][e] = (cp & 2) ? hi : lo;
        }
    }
    float r2[2][4];
    #pragma unroll
    for (int r = 0; r < 2; ++r) {
        #pragma unroll
        for (int e = 0; e < 4; ++e) {
            float lo = r4v[r][e]     + __shfl_xor(r4v[r][e], 4);
            float hi = r4v[r + 2][e] + __shfl_xor(r4v[r + 2][e], 4);
            r2[r][e] = (cp & 4) ? hi : lo;
        }
    }
    float r1[4];
    #pragma unroll
    for (int e = 0; e < 4; ++e) {
        float lo = r2[0][e] + __shfl_xor(r2[0][e], 8);
        float hi = r2[1][e] + __shfl_xor(r2[1][e], 8);
        r1[e] = (cp & 8) ? hi : lo;
    }
    int ko = ((cp & 1) << 3) | (((cp >> 1) & 1) << 2) | (((cp >> 2) & 1) << 1)
           | ((cp >> 3) & 1);

    float4 st;
    st.x = r1[0]; st.y = r1[1]; st.z = r1[2]; st.w = r1[3];
    *(float4*)(cw + (size_t)b * 65536 + (size_t)ko * 4096 + ich * 64 + il * 4) = st;

    // BN partials over this block's 64 i: xor-reduce lane bits 4,5 + LDS combine
    float s1 = r1[0] + r1[1] + r1[2] + r1[3];
    float s2 = r1[0]*r1[0] + r1[1]*r1[1] + r1[2]*r1[2] + r1[3]*r1[3];
    #pragma unroll
    for (int m = 16; m <= 32; m <<= 1) {
        s1 += __shfl_xor(s1, m);
        s2 += __shfl_xor(s2, m);
    }
    if ((t & 48) == 0) { bnl[wv][ko] = s1; bnl[wv][16 + ko] = s2; }
    __syncthreads();
    if (t < 32) {
        pbn[bid * 32 + t] = bnl[0][t] + bnl[1][t] + bnl[2][t] + bnl[3][t];
    }
}

// ---------------- Kernel 2: BN apply + partials for Sr/Srr/Sx/Sxx + Cross ----------
// grid 512 = 4(b) x 128(slab of 32 i); block 256 (t = channel c). No atomics in
// PCX path — all outputs are per-block plain stores.
template <bool PCX>
__global__ __launch_bounds__(256, 2) void k_main(const float* __restrict__ x,
                                                 const float* __restrict__ gamma,
                                                 const float* __restrict__ beta,
                                                 float* __restrict__ ws,
                                                 float* __restrict__ pcx) {
    __shared__ float xl[8192];       // xl[i*256 + (c^i)] : XOR swizzle
    __shared__ float rl[512];
    __shared__ float red1[256], red2[256];
    __shared__ float bnred[256];     // [row0<8][col<32]
    int bid = blockIdx.x;
    int b   = bid >> 7;
    int s   = bid & 127;
    int kp  = s >> 3;                // flat slab of 512 sits inside one original channel
    int t   = threadIdx.x;

    // BN stats: deterministic reduce of k_conv's 256x32 partials
    {
        int col = t & 31, row0 = t >> 5;
        float p = 0.f;
        for (int m = row0; m < 256; m += 8) p += ws[OFF_PBN + m * 32 + col];
        bnred[t] = p;
    }
    __syncthreads();
    float s1 = 0.f, s2 = 0.f;
    #pragma unroll
    for (int j = 0; j < 8; ++j) {
        s1 += bnred[j * 32 + kp];
        s2 += bnred[j * 32 + 16 + kp];
    }
    float mean = s1 * (1.f / 16384.f);
    float var  = s2 * (1.f / 16384.f) - mean * mean;
    float aa   = gamma[kp] * rsqrtf(var + BN_EPS);
    float bb   = beta[kp] - mean * aa;

    // stage x slab (256 c x 32 i): coalesced float4 reads, swizzled LDS writes
    #pragma unroll
    for (int j = 0; j < 8; ++j) {
        int F  = j * 256 + t;        // 2048 float4s
        int cc = F >> 3, i4 = F & 7;
        const float* pa = x + (size_t)(b * 256 + cc) * 4096 + s * 32 + i4 * 4;
        float4 v = *(const float4*)pa;
        int ib = i4 * 4;
        xl[(ib + 0) * 256 + (cc ^ (ib + 0))] = v.x;
        xl[(ib + 1) * 256 + (cc ^ (ib + 1))] = v.y;
        xl[(ib + 2) * 256 + (cc ^ (ib + 2))] = v.z;
        xl[(ib + 3) * 256 + (cc ^ (ib + 3))] = v.w;
    }

    // r values: BN+ReLU of this slab's 512 flat cw entries; k2 = flat & 15
    const float* cwp = ws + OFF_CW + (size_t)b * 65536 + (size_t)kp * 4096
                     + (size_t)(s & 7) * 512;
    float sr = 0.f, srr = 0.f;
    #pragma unroll
    for (int j = 0; j < 2; ++j) {
        float v = cwp[t + j * 256];
        v = fmaxf(fmaf(v, aa, bb), 0.f);
        rl[t + j * 256] = v;
        sr += v; srr += v * v;
    }
    red1[t] = sr; red2[t] = srr;
    __syncthreads();

    // per-k2 partials for this block: plain stores (k_final derives SR/SRR/SCALE)
    if (t < 16) {
        float a1 = 0.f, a2 = 0.f;
        for (int m = t; m < 256; m += 16) { a1 += red1[m]; a2 += red2[m]; }
        ws[OFF_PSR + bid * 32 + t]      = a1;
        ws[OFF_PSR + bid * 32 + 16 + t] = a2;
    }

    // Cross partial: thread = channel c; 32 i from swizzled LDS; rl broadcast
    int c = t;
    float acc[16];
    #pragma unroll
    for (int k = 0; k < 16; ++k) acc[k] = 0.f;
    float xs = 0.f, xs2 = 0.f;
    #pragma unroll
    for (int ii = 0; ii < 32; ++ii) {
        float xv = xl[ii * 256 + (c ^ ii)];
        xs += xv; xs2 += xv * xv;
        FMA16(xv, rl + ii * 16);
    }

    ws[OFF_PSX  + bid * 256 + c] = xs;
    ws[OFF_PSXX + bid * 256 + c] = xs2;
    if (PCX) {
        float* pp = pcx + (size_t)(bid * 16) * 256 + c;
        #pragma unroll
        for (int k = 0; k < 16; ++k) pp[(size_t)k * 256] = acc[k];
    } else {
        #pragma unroll
        for (int k = 0; k < 16; ++k)
            atomicAdd(ws + OFF_CROSSR + (b * 16 + k) * 256 + c, acc[k]);
    }
}

// ---------------- Kernel 3: reduce Cross partials (single writer, no atomics) ------
// grid 256 = 4(b) x 16(k) x 4(sg of 32 slabs); block 256 (t = c).
__global__ __launch_bounds__(256) void k_red(const float* __restrict__ pcx,
                                             float* __restrict__ crossr) {
    int bid = blockIdx.x;
    int b  = bid >> 6;
    int k  = (bid >> 2) & 15;
    int sg = bid & 3;
    int c  = threadIdx.x;
    float acc = 0.f;
    #pragma unroll 8
    for (int m = 0; m < 32; ++m) {
        int sl = sg * 32 + m;
        acc += pcx[(size_t)((b * 128 + sl) * 16 + k) * 256 + c];
    }
    crossr[((sg * 4 + b) * 16 + k) * 256 + c] = acc;
}

// ---------------- Kernel 4: final reductions + softmax + output ----------------
// grid 4 (b), block 256 (t = c). Derives SR/SRR/SCALE from psr partials.
__global__ __launch_bounds__(256) void k_final(const float* __restrict__ ws,
                                               float* __restrict__ out) {
    __shared__ float srl[4096];    // [s<128][32]
    __shared__ float fin[48];      // SR[16], SRR[16], SCALE[16]
    int b = blockIdx.x;
    int t = threadIdx.x;

    const float* psr = ws + OFF_PSR + (size_t)b * 128 * 32;
    #pragma unroll
    for (int j = 0; j < 16; ++j) srl[j * 256 + t] = psr[j * 256 + t];
    __syncthreads();

    if (t < 16) {
        float v = 0.f;
        for (int s = 0; s < 128; ++s) v += srl[s * 32 + t];
        fin[t] = v;                                   // SR[k2]
    } else if (t < 32) {
        int k = t - 16;
        float v = 0.f;
        for (int s = 0; s < 128; ++s) v += srl[s * 32 + 16 + k];
        fin[16 + k] = v;                              // SRR[k2]
    } else if (t < 48) {
        int kp = t - 32;
        float v = 0.f;
        for (int s = kp * 8; s < kp * 8 + 8; ++s)
            for (int k2 = 0; k2 < 16; ++k2) v += srl[s * 32 + k2];
        fin[32 + kp] = v;                             // SCALE[kp] (pre /4096)
    }
    __syncthreads();

    int c = t;
    float sx = 0.f, sxx = 0.f;
    const float* psx  = ws + OFF_PSX  + (size_t)b * 128 * 256;
    const float* psxx = ws + OFF_PSXX + (size_t)b * 128 * 256;
    for (int p = 0; p < 128; ++p) {
        sx  += psx[p * 256 + c];
        sxx += psxx[p * 256 + c];
    }

    float sl2[16];
    float mx = -1e30f;
    #pragma unroll
    for (int k = 0; k < 16; ++k) {
        float cr = 0.f;
        #pragma unroll
        for (int sg = 0; sg < 4; ++sg)
            cr += ws[OFF_CROSSR + ((sg * 4 + b) * 16 + k) * 256 + c];
        float v = fin[32 + k] * (1.f / 4096.f) * (sxx - 2.f * cr + fin[16 + k]);
        sl2[k] = v;
        mx = fmaxf(mx, v);
    }
    float den = 0.f;
    #pragma unroll
    for (int k = 0; k < 16; ++k) {
        float e = __expf(sl2[k] - mx);
        sl2[k] = e;
        den += e;
    }
    float inv = 1.f / den;
    #pragma unroll
    for (int k = 0; k < 16; ++k)
        out[(size_t)(b * 16 + k) * 256 + c] = sl2[k] * inv * (sx - fin[k]);
}

extern "C" void kernel_launch(void* const* d_in, const int* in_sizes, int n_in,
                              void* d_out, int out_size, void* d_ws, size_t ws_size,
                              hipStream_t stream) {
    const float* x     = (const float*)d_in[0];
    const float* w     = (const float*)d_in[1];
    const float* gamma = (const float*)d_in[2];
    const float* beta  = (const float*)d_in[3];
    float* ws  = (float*)d_ws;
    float* out = (float*)d_out;

    bool use_pcx = ws_size >= WS_NEED;   // constant across calls: graph-safe

    k_conv<<<256, 256, 0, stream>>>(x, w, ws + OFF_CW, ws + OFF_PBN);
    if (use_pcx) {
        k_main<true><<<512, 256, 0, stream>>>(x, gamma, beta, ws, ws + OFF_PCX);
        k_red<<<256, 256, 0, stream>>>(ws + OFF_PCX, ws + OFF_CROSSR);
    } else {
        hipMemsetAsync(ws + OFF_CROSSR, 0, 65536 * sizeof(float), stream);
        k_main<false><<<512, 256, 0, stream>>>(x, gamma, beta, ws, nullptr);
    }
    k_final<<<4, 256, 0, stream>>>(ws, out);
}